// Round 1
// 1220.658 us; speedup vs baseline: 1.3569x; 1.3569x over previous
//
#include <hip/hip_runtime.h>

// B=128, S=196, K=512, T=15, V=32000, E=H=512
typedef _Float16 half_t;
typedef float    floatx4 __attribute__((ext_vector_type(4)));
typedef _Float16 halfx8  __attribute__((ext_vector_type(8)));
typedef _Float16 halfx2  __attribute__((ext_vector_type(2)));

__device__ __forceinline__ float tanh_f(float x) {
  float e = __expf(2.0f * x);
  return 1.0f - 2.0f / (e + 1.0f);
}
__device__ __forceinline__ float sigmoid_f(float x) {
  return 1.0f / (1.0f + __expf(-x));
}

// async global -> LDS, 16B per lane (dest = wave-uniform base + lane*16)
__device__ __forceinline__ void gl16(const void* g, void* s) {
  __builtin_amdgcn_global_load_lds((__attribute__((address_space(1))) unsigned int*)g,
                                   (__attribute__((address_space(3))) unsigned int*)s,
                                   16, 0, 0);
}

// ---------------- f32 -> f16 convert ----------------
__global__ __launch_bounds__(256) void k_cvt_f16(const float* __restrict__ src,
                                                 half_t* __restrict__ dst, int n) {
  int i = (blockIdx.x * 256 + threadIdx.x) * 4;
  if (i < n) {
    float4 v = *(const float4*)(src + i);
    halfx2 a; a[0] = (half_t)v.x; a[1] = (half_t)v.y;
    halfx2 b; b[0] = (half_t)v.z; b[1] = (half_t)v.w;
    *(halfx2*)(dst + i) = a;
    *(halfx2*)(dst + i + 2) = b;
  }
}

// split wih (1536x1024 f32) into wihx (cols 0:512) and wihc (cols 512:1024), f16
__global__ __launch_bounds__(256) void k_wihsplit(const float* __restrict__ wih,
                                                  half_t* __restrict__ wx,
                                                  half_t* __restrict__ wc) {
  int row = blockIdx.x, j = threadIdx.x * 2;
  float2 a = *(const float2*)(wih + (size_t)row * 1024 + j);
  float2 b = *(const float2*)(wih + (size_t)row * 1024 + 512 + j);
  halfx2 ax; ax[0] = (half_t)a.x; ax[1] = (half_t)a.y;
  halfx2 bx; bx[0] = (half_t)b.x; bx[1] = (half_t)b.y;
  *(halfx2*)(wx + (size_t)row * 512 + j) = ax;
  *(halfx2*)(wc + (size_t)row * 512 + j) = bx;
}

// ---------------- embedding gather -> f16 (rows b*15+t) ----------------
__global__ __launch_bounds__(256) void k_gather(const float* __restrict__ emb,
                                                const int* __restrict__ cap,
                                                half_t* __restrict__ dst) {
  int row = blockIdx.x;              // b*15 + t
  int b = row / 15, t = row - b * 15;
  int c = cap[b * 16 + t];
  const float* s = emb + (size_t)c * 512;
  int e = threadIdx.x * 2;
  float2 v = *(const float2*)(s + e);
  halfx2 o; o[0] = (half_t)v.x; o[1] = (half_t)v.y;
  *(halfx2*)(dst + (size_t)row * 512 + e) = o;
}

// biasc[0:512]=0, biasc[512:1024]=fc0_b
__global__ __launch_bounds__(256) void k_biasc(const float* __restrict__ fc0b,
                                               float* __restrict__ biasc) {
  int i = blockIdx.x * 256 + threadIdx.x;
  biasc[i] = (i < 512) ? 0.f : fc0b[i - 512];
}

__global__ __launch_bounds__(256) void k_zero(float4* p) {
  p[blockIdx.x * 256 + threadIdx.x] = make_float4(0.f, 0.f, 0.f, 0.f);
}

// ---------------- LDS-staged MFMA GEMM (m97 structure) ----------------
// C[m][n] = sum_k A[m][k]*B[n][k] (+bias[n]); tile 128x128, BK=32, 4 waves.
// A is f32 (staged raw, converted at fragment read) or f16. B is f16.
template <bool A_F32, bool OUT_F16>
__device__ __forceinline__ void gemm128_body(const void* __restrict__ Ap,
                                             const half_t* __restrict__ Bp,
                                             const float* __restrict__ bias,
                                             void* __restrict__ Cp,
                                             const int Kd, const int ldc,
                                             const int m0, const int n0) {
  constexpr int ABYTES = A_F32 ? (128 * 32 * 4) : (128 * 32 * 2);
  constexpr int BBYTES = 128 * 32 * 2;
  __shared__ __align__(16) char smem[2 * ABYTES + 2 * BBYTES];

  const int l = threadIdx.x & 63;
  const int w = threadIdx.x >> 6;

  // per-lane staging source pointers (wave w stages rows [w*32, w*32+32))
  const float*  gAf = nullptr;
  const half_t* gAh = nullptr;
  if constexpr (A_F32) {
    gAf = (const float*)Ap + (size_t)(m0 + w * 32 + (l >> 3)) * Kd + (l & 7) * 4;
  } else {
    gAh = (const half_t*)Ap + (size_t)(m0 + w * 32 + (l >> 2)) * Kd + (l & 3) * 8;
  }
  const half_t* gB = Bp + (size_t)(n0 + w * 32 + (l >> 2)) * Kd + (l & 3) * 8;

  const int fr = l & 15;
  const int kq = (l >> 4) * 8;
  const int mh = (w & 1) * 64;
  const int nh = (w >> 1) * 64;

  floatx4 acc[4][4];
#pragma unroll
  for (int i = 0; i < 4; ++i)
#pragma unroll
    for (int j = 0; j < 4; ++j) { floatx4 z = {0.f, 0.f, 0.f, 0.f}; acc[i][j] = z; }

  const int NT = Kd >> 5;

  auto stage = [&](int tt) {
    const int k0 = tt * 32;
    char* aD = smem + (tt & 1) * ABYTES;
    char* bD = smem + 2 * ABYTES + (tt & 1) * BBYTES;
    if constexpr (A_F32) {
      const float* g = gAf + k0;
#pragma unroll
      for (int j = 0; j < 4; ++j)
        gl16(g + (size_t)j * 8 * Kd, aD + (w * 32 + j * 8) * 128);
    } else {
      const half_t* g = gAh + k0;
      gl16(g, aD + (w * 32) * 64);
      gl16(g + (size_t)16 * Kd, aD + (w * 32 + 16) * 64);
    }
    const half_t* g2 = gB + k0;
    gl16(g2, bD + (w * 32) * 64);
    gl16(g2 + (size_t)16 * Kd, bD + (w * 32 + 16) * 64);
  };

  stage(0);

  for (int t = 0; t < NT; ++t) {
    __syncthreads();                 // drains stage(t) (compiler emits vmcnt(0) before barrier)
    if (t + 1 < NT) stage(t + 1);    // prefetch into other buffer
    const char* aB = smem + (t & 1) * ABYTES;
    const char* bB = smem + 2 * ABYTES + (t & 1) * BBYTES;
    halfx8 af[4], bf[4];
#pragma unroll
    for (int i = 0; i < 4; ++i) {
      if constexpr (A_F32) {
        const float* la = (const float*)aB + (size_t)(mh + i * 16 + fr) * 32 + kq;
        float4 v0 = *(const float4*)la;
        float4 v1 = *(const float4*)(la + 4);
        halfx8 a;
        a[0] = (half_t)v0.x; a[1] = (half_t)v0.y; a[2] = (half_t)v0.z; a[3] = (half_t)v0.w;
        a[4] = (half_t)v1.x; a[5] = (half_t)v1.y; a[6] = (half_t)v1.z; a[7] = (half_t)v1.w;
        af[i] = a;
      } else {
        af[i] = *(const halfx8*)((const half_t*)aB + (size_t)(mh + i * 16 + fr) * 32 + kq);
      }
      bf[i] = *(const halfx8*)((const half_t*)bB + (size_t)(nh + i * 16 + fr) * 32 + kq);
    }
#pragma unroll
    for (int i = 0; i < 4; ++i)
#pragma unroll
      for (int j = 0; j < 4; ++j)
        acc[i][j] = __builtin_amdgcn_mfma_f32_16x16x32_f16(af[i], bf[j], acc[i][j], 0, 0, 0);
  }

#pragma unroll
  for (int j = 0; j < 4; ++j) {
    const int n = n0 + nh + j * 16 + fr;
    const float bv = bias ? bias[n] : 0.0f;
#pragma unroll
    for (int i = 0; i < 4; ++i) {
      const int mb = m0 + mh + i * 16 + (l >> 4) * 4;
#pragma unroll
      for (int r = 0; r < 4; ++r) {
        const float v = acc[i][j][r] + bv;
        const size_t ci = (size_t)(mb + r) * ldc + n;
        if constexpr (OUT_F16) ((half_t*)Cp)[ci] = (half_t)v;
        else                   ((float*)Cp)[ci] = v;
      }
    }
  }
}

// generic wrapper: grid.x = n-tiles (fast), grid.y = m-tiles
template <bool A_F32, bool OUT_F16>
__global__ __launch_bounds__(256) void k_gemm_lds(const void* __restrict__ Ap,
                                                  const half_t* __restrict__ Bp,
                                                  const float* __restrict__ bias,
                                                  void* __restrict__ Cp,
                                                  int Kd, int ldc) {
  gemm128_body<A_F32, OUT_F16>(Ap, Bp, bias, Cp, Kd, ldc,
                               blockIdx.y * 128, blockIdx.x * 128);
}

// fused fc2 + [gh|q]: blocks [0,250): C=out (+fc2_b); [250,266): C=ghq (f32, ldc 2048)
__global__ __launch_bounds__(256) void k_fc2gru_lds(const half_t* __restrict__ hh,
                                                    const half_t* __restrict__ fc2w,
                                                    const float* __restrict__ fc2b,
                                                    const half_t* __restrict__ bcat2,
                                                    float* __restrict__ outp,
                                                    float* __restrict__ ghq) {
  const bool isfc2 = blockIdx.x < 250;
  const half_t* B = isfc2 ? fc2w : bcat2;
  const float* bias = isfc2 ? fc2b : nullptr;
  void* C = isfc2 ? (void*)outp : (void*)ghq;
  const int ldc = isfc2 ? 480000 : 2048;
  const int n0 = (isfc2 ? blockIdx.x : (blockIdx.x - 250)) * 128;
  gemm128_body<false, false>(hh, B, bias, C, 512, ldc, 0, n0);
}

// ---------------- scores: one wave per (b,s): tanh(q_b + kp_bs) . attv ----------------
__global__ __launch_bounds__(256) void k_scores(const half_t* __restrict__ kpfp,
                                                const float* __restrict__ ghq,
                                                const float* __restrict__ attv,
                                                float* __restrict__ scores) {
  int w = blockIdx.x * 4 + (threadIdx.x >> 6);   // 0..25087 == b*196+s
  int l = threadIdx.x & 63;
  int b = w / 196;
  halfx8 kv = *(const halfx8*)(kpfp + (size_t)w * 1024 + l * 8);
  const float* qr = ghq + (size_t)b * 2048 + 1536 + l * 8;
  float4 q0 = *(const float4*)qr;
  float4 q1 = *(const float4*)(qr + 4);
  float4 a0 = *(const float4*)(attv + l * 8);
  float4 a1 = *(const float4*)(attv + l * 8 + 4);
  float acc = a0.x * tanh_f(q0.x + (float)kv[0]);
  acc += a0.y * tanh_f(q0.y + (float)kv[1]);
  acc += a0.z * tanh_f(q0.z + (float)kv[2]);
  acc += a0.w * tanh_f(q0.w + (float)kv[3]);
  acc += a1.x * tanh_f(q1.x + (float)kv[4]);
  acc += a1.y * tanh_f(q1.y + (float)kv[5]);
  acc += a1.z * tanh_f(q1.z + (float)kv[6]);
  acc += a1.w * tanh_f(q1.w + (float)kv[7]);
#pragma unroll
  for (int off = 32; off > 0; off >>= 1) acc += __shfl_xor(acc, off, 64);
  if (l == 0) scores[w] = acc;
}

// ---------------- softmax + ctx = w @ featp (f16 out) ----------------
__global__ __launch_bounds__(256) void k_ctx(const float* __restrict__ scores,
                                             const half_t* __restrict__ kpfp,
                                             half_t* __restrict__ ctxo) {
  const int b = blockIdx.x, kt = blockIdx.y * 128, t = threadIdx.x;
  __shared__ float sw[196], red[256];
  float sc = (t < 196) ? scores[b * 196 + t] : -1e30f;
  red[t] = sc; __syncthreads();
  for (int o = 128; o > 0; o >>= 1) { if (t < o) red[t] = fmaxf(red[t], red[t + o]); __syncthreads(); }
  float mx = red[0]; __syncthreads();
  float e = (t < 196) ? __expf(sc - mx) : 0.f;
  red[t] = e; __syncthreads();
  for (int o = 128; o > 0; o >>= 1) { if (t < o) red[t] += red[t + o]; __syncthreads(); }
  float inv = 1.0f / red[0];
  if (t < 196) sw[t] = e * inv;
  __syncthreads();
  const int kk = t & 127, half = t >> 7, s0 = half * 98;
  const half_t* fp = kpfp + (size_t)(b * 196 + s0) * 1024 + 512 + kt + kk;
  float acc = 0.f;
#pragma unroll 7
  for (int i = 0; i < 98; ++i) acc += sw[s0 + i] * (float)fp[(size_t)i * 1024];
  red[t] = acc; __syncthreads();
  if (t < 128) ctxo[(size_t)b * 512 + kt + t] = (half_t)(red[t] + red[t + 128]);
}

// ---------------- GRU gates, elementwise ----------------
__global__ __launch_bounds__(256) void k_gates(const float* __restrict__ gix,
                                               const float* __restrict__ gic,
                                               const float* __restrict__ ghq,
                                               const float* __restrict__ bih,
                                               const float* __restrict__ bhh,
                                               float* __restrict__ hbuf,
                                               half_t* __restrict__ hh, int step) {
  int idx = blockIdx.x * 256 + threadIdx.x;  // 0..65535
  int b = idx >> 9, n = idx & 511;
  const float* gx = gix + (size_t)(b * 15 + step) * 1536;
  const float* gc = gic + (size_t)b * 1536;
  const float* gh = ghq + (size_t)b * 2048;
  float ir  = gx[n]        + gc[n]        + bih[n];
  float iz  = gx[n + 512]  + gc[n + 512]  + bih[n + 512];
  float in_ = gx[n + 1024] + gc[n + 1024] + bih[n + 1024];
  float hr  = gh[n]        + bhh[n];
  float hz  = gh[n + 512]  + bhh[n + 512];
  float hn  = gh[n + 1024] + bhh[n + 1024];
  float r = sigmoid_f(ir + hr);
  float z = sigmoid_f(iz + hz);
  float nn = tanh_f(in_ + r * hn);
  float hv = (1.0f - z) * nn + z * hbuf[idx];
  hbuf[idx] = hv;
  hh[idx] = (half_t)hv;
}

extern "C" void kernel_launch(void* const* d_in, const int* in_sizes, int n_in,
                              void* d_out, int out_size, void* d_ws, size_t ws_size,
                              hipStream_t stream) {
  (void)in_sizes; (void)n_in; (void)out_size; (void)ws_size;
  const float* features = (const float*)d_in[0];
  const int*   captions = (const int*)d_in[1];
  const float* emb      = (const float*)d_in[2];
  const float* fc1_w    = (const float*)d_in[3];
  const float* fc1_b    = (const float*)d_in[4];
  const float* att_wq   = (const float*)d_in[5];
  const float* att_wk   = (const float*)d_in[6];
  const float* att_v    = (const float*)d_in[7];
  const float* fc0_w    = (const float*)d_in[8];
  const float* fc0_b    = (const float*)d_in[9];
  const float* gru_wih  = (const float*)d_in[10];
  const float* gru_whh  = (const float*)d_in[11];
  const float* gru_bih  = (const float*)d_in[12];
  const float* gru_bhh  = (const float*)d_in[13];
  const float* fc2_w    = (const float*)d_in[14];
  const float* fc2_b    = (const float*)d_in[15];
  float* out = (float*)d_out;

  // workspace layout (~109 MB)
  char* p = (char*)d_ws;
  half_t* kpfp   = (half_t*)p; p += (size_t)25088 * 1024 * 2; // [:,0:512]=kp, [:,512:1024]=featp+fc0_b
  half_t* fc2w_h = (half_t*)p; p += (size_t)32000 * 512 * 2;
  float*  gix    = (float*)p;  p += (size_t)1920 * 1536 * 4;  // x-path GRU gates, all t
  half_t* wihx_h = (half_t*)p; p += (size_t)1536 * 512 * 2;
  half_t* wihc_h = (half_t*)p; p += (size_t)1536 * 512 * 2;
  half_t* bcat2  = (half_t*)p; p += (size_t)2048 * 512 * 2;   // rows 0:1536=whh, 1536:2048=wq
  half_t* wkfc0  = (half_t*)p; p += (size_t)1024 * 512 * 2;   // rows 0:512=att_wk, 512:1024=fc0_w
  half_t* fc1w_h = (half_t*)p; p += (size_t)512 * 512 * 2;
  half_t* embg_h = (half_t*)p; p += (size_t)1920 * 512 * 2;
  half_t* xproj_h= (half_t*)p; p += (size_t)1920 * 512 * 2;
  float*  biasc  = (float*)p;  p += (size_t)1024 * 4;
  float*  ghq    = (float*)p;  p += (size_t)128 * 2048 * 4;   // cols 0:1536=gh, 1536:2048=q
  float*  hbuf   = (float*)p;  p += (size_t)128 * 512 * 4;    // contiguous after ghq (zeroed together)
  float*  scores = (float*)p;  p += (size_t)128 * 196 * 4;
  float*  gic    = (float*)p;  p += (size_t)128 * 1536 * 4;
  half_t* ctxo   = (half_t*)p; p += (size_t)128 * 512 * 2;
  half_t* h_h    = (half_t*)p; p += (size_t)128 * 512 * 2;

  // ---- precompute ----
  k_cvt_f16<<<dim3(16000), 256, 0, stream>>>(fc2_w, fc2w_h, 32000 * 512);
  k_cvt_f16<<<dim3(256),   256, 0, stream>>>(fc1_w, fc1w_h, 512 * 512);
  k_cvt_f16<<<dim3(256),   256, 0, stream>>>(att_wk, wkfc0, 512 * 512);
  k_cvt_f16<<<dim3(256),   256, 0, stream>>>(fc0_w, wkfc0 + (size_t)512 * 512, 512 * 512);
  k_cvt_f16<<<dim3(768),   256, 0, stream>>>(gru_whh, bcat2, 1536 * 512);
  k_cvt_f16<<<dim3(256),   256, 0, stream>>>(att_wq, bcat2 + (size_t)1536 * 512, 512 * 512);
  k_wihsplit<<<dim3(1536), 256, 0, stream>>>(gru_wih, wihx_h, wihc_h);
  k_gather<<<dim3(1920), 256, 0, stream>>>(emb, captions, embg_h);
  k_biasc<<<dim3(4), 256, 0, stream>>>(fc0_b, biasc);
  // zero ghq (1 MB) + hbuf (256 KB): 81920 float4
  k_zero<<<dim3(320), 256, 0, stream>>>((float4*)ghq);
  // xproj = embg @ fc1_w^T + fc1_b  (1920 x 512, f16 out)
  k_gemm_lds<false, true><<<dim3(4, 15), 256, 0, stream>>>(embg_h, fc1w_h, fc1_b, xproj_h, 512, 512);
  // kpfp = features @ [wk|fc0]^T + [0|fc0_b]  (25088 x 1024, f16 out; A stays f32)
  k_gemm_lds<true, true><<<dim3(8, 196), 256, 0, stream>>>(features, wkfc0, biasc, kpfp, 512, 1024);
  // gix = xproj @ wihx^T  (1920 x 1536, f32 out)
  k_gemm_lds<false, false><<<dim3(12, 15), 256, 0, stream>>>(xproj_h, wihx_h, nullptr, gix, 512, 1536);

  // ---- decode loop ----
  for (int t = 0; t < 15; ++t) {
    k_scores<<<dim3(6272), 256, 0, stream>>>(kpfp, ghq, att_v, scores);
    k_ctx<<<dim3(128, 4), 256, 0, stream>>>(scores, kpfp, ctxo);
    // gic = ctxo @ wihc^T  (128 x 1536)
    k_gemm_lds<false, false><<<dim3(12, 1), 256, 0, stream>>>(ctxo, wihc_h, nullptr, gic, 512, 1536);
    k_gates<<<dim3(256), 256, 0, stream>>>(gix, gic, ghq, gru_bih, gru_bhh, hbuf, h_h, t);
    // out[:,t,:] = h @ fc2^T + fc2_b ; ghq = h @ [whh|wq]^T (for step t+1)
    k_fc2gru_lds<<<dim3(266), 256, 0, stream>>>(h_h, fc2w_h, fc2_b, bcat2, out + (size_t)t * 32000, ghq);
  }
}

// Round 2
// 1206.452 us; speedup vs baseline: 1.3729x; 1.0118x over previous
//
#include <hip/hip_runtime.h>

// B=128, S=196, K=512, T=15, V=32000, E=H=512
typedef _Float16 half_t;
typedef float    floatx4 __attribute__((ext_vector_type(4)));
typedef _Float16 halfx8  __attribute__((ext_vector_type(8)));
typedef _Float16 halfx2  __attribute__((ext_vector_type(2)));

__device__ __forceinline__ float tanh_f(float x) {
  float e = __expf(2.0f * x);
  return 1.0f - 2.0f / (e + 1.0f);
}
__device__ __forceinline__ float sigmoid_f(float x) {
  return 1.0f / (1.0f + __expf(-x));
}

// async global -> LDS, 16B per lane (dest = wave-uniform base + lane*16)
__device__ __forceinline__ void gl16(const void* g, void* s) {
  __builtin_amdgcn_global_load_lds((__attribute__((address_space(1))) unsigned int*)g,
                                   (__attribute__((address_space(3))) unsigned int*)s,
                                   16, 0, 0);
}

// bijective XCD swizzle (m204): hardware bid -> work id, contiguous chunk per XCD
__device__ __forceinline__ int xcd_swz(int bid, int nwg) {
  int q = nwg >> 3, r = nwg & 7, x = bid & 7, p = bid >> 3;
  return (x < r ? x * (q + 1) : r * (q + 1) + (x - r) * q) + p;
}

// ---------------- f32 -> f16 convert ----------------
__global__ __launch_bounds__(256) void k_cvt_f16(const float* __restrict__ src,
                                                 half_t* __restrict__ dst, int n) {
  int i = (blockIdx.x * 256 + threadIdx.x) * 4;
  if (i < n) {
    float4 v = *(const float4*)(src + i);
    halfx2 a; a[0] = (half_t)v.x; a[1] = (half_t)v.y;
    halfx2 b; b[0] = (half_t)v.z; b[1] = (half_t)v.w;
    *(halfx2*)(dst + i) = a;
    *(halfx2*)(dst + i + 2) = b;
  }
}

// split wih (1536x1024 f32) into wihx (cols 0:512) and wihc (cols 512:1024), f16
__global__ __launch_bounds__(256) void k_wihsplit(const float* __restrict__ wih,
                                                  half_t* __restrict__ wx,
                                                  half_t* __restrict__ wc) {
  int row = blockIdx.x, j = threadIdx.x * 2;
  float2 a = *(const float2*)(wih + (size_t)row * 1024 + j);
  float2 b = *(const float2*)(wih + (size_t)row * 1024 + 512 + j);
  halfx2 ax; ax[0] = (half_t)a.x; ax[1] = (half_t)a.y;
  halfx2 bx; bx[0] = (half_t)b.x; bx[1] = (half_t)b.y;
  *(halfx2*)(wx + (size_t)row * 512 + j) = ax;
  *(halfx2*)(wc + (size_t)row * 512 + j) = bx;
}

// ---------------- embedding gather -> f16 (rows b*15+t) ----------------
__global__ __launch_bounds__(256) void k_gather(const float* __restrict__ emb,
                                                const int* __restrict__ cap,
                                                half_t* __restrict__ dst) {
  int row = blockIdx.x;              // b*15 + t
  int b = row / 15, t = row - b * 15;
  int c = cap[b * 16 + t];
  const float* s = emb + (size_t)c * 512;
  int e = threadIdx.x * 2;
  float2 v = *(const float2*)(s + e);
  halfx2 o; o[0] = (half_t)v.x; o[1] = (half_t)v.y;
  *(halfx2*)(dst + (size_t)row * 512 + e) = o;
}

// biasc[0:512]=0, biasc[512:1024]=fc0_b
__global__ __launch_bounds__(256) void k_biasc(const float* __restrict__ fc0b,
                                               float* __restrict__ biasc) {
  int i = blockIdx.x * 256 + threadIdx.x;
  biasc[i] = (i < 512) ? 0.f : fc0b[i - 512];
}

__global__ __launch_bounds__(256) void k_zero(float4* p) {
  p[blockIdx.x * 256 + threadIdx.x] = make_float4(0.f, 0.f, 0.f, 0.f);
}

// ---------------- LDS-staged MFMA GEMM (m97 structure), f16 A and B ----------------
// C[m][n] = sum_k A[m][k]*B[n][k] (+bias[n]); tile 128x128, BK=32, 4 waves.
template <bool OUT_F16>
__device__ __forceinline__ void gemm128_body(const half_t* __restrict__ Ap,
                                             const half_t* __restrict__ Bp,
                                             const float* __restrict__ bias,
                                             void* __restrict__ Cp,
                                             const int Kd, const int ldc,
                                             const int m0, const int n0) {
  constexpr int ABYTES = 128 * 32 * 2;
  constexpr int BBYTES = 128 * 32 * 2;
  __shared__ __align__(16) char smem[2 * ABYTES + 2 * BBYTES];

  const int l = threadIdx.x & 63;
  const int w = threadIdx.x >> 6;

  // per-lane staging source (wave w stages rows [w*32, w*32+32)): 4 lanes/row x 16B
  const half_t* gA = Ap + (size_t)(m0 + w * 32 + (l >> 2)) * Kd + (l & 3) * 8;
  const half_t* gB = Bp + (size_t)(n0 + w * 32 + (l >> 2)) * Kd + (l & 3) * 8;

  const int fr = l & 15;
  const int kq = (l >> 4) * 8;
  const int mh = (w & 1) * 64;
  const int nh = (w >> 1) * 64;

  floatx4 acc[4][4];
#pragma unroll
  for (int i = 0; i < 4; ++i)
#pragma unroll
    for (int j = 0; j < 4; ++j) { floatx4 z = {0.f, 0.f, 0.f, 0.f}; acc[i][j] = z; }

  const int NT = Kd >> 5;

  auto stage = [&](int tt) {
    const int k0 = tt * 32;
    char* aD = smem + (tt & 1) * ABYTES;
    char* bD = smem + 2 * ABYTES + (tt & 1) * BBYTES;
    const half_t* g = gA + k0;
    gl16(g, aD + (w * 32) * 64);
    gl16(g + (size_t)16 * Kd, aD + (w * 32 + 16) * 64);
    const half_t* g2 = gB + k0;
    gl16(g2, bD + (w * 32) * 64);
    gl16(g2 + (size_t)16 * Kd, bD + (w * 32 + 16) * 64);
  };

  stage(0);

  for (int t = 0; t < NT; ++t) {
    __syncthreads();                 // drains stage(t)
    if (t + 1 < NT) stage(t + 1);    // prefetch into other buffer
    const char* aB = smem + (t & 1) * ABYTES;
    const char* bB = smem + 2 * ABYTES + (t & 1) * BBYTES;
    halfx8 af[4], bf[4];
#pragma unroll
    for (int i = 0; i < 4; ++i) {
      af[i] = *(const halfx8*)((const half_t*)aB + (size_t)(mh + i * 16 + fr) * 32 + kq);
      bf[i] = *(const halfx8*)((const half_t*)bB + (size_t)(nh + i * 16 + fr) * 32 + kq);
    }
#pragma unroll
    for (int i = 0; i < 4; ++i)
#pragma unroll
      for (int j = 0; j < 4; ++j)
        acc[i][j] = __builtin_amdgcn_mfma_f32_16x16x32_f16(af[i], bf[j], acc[i][j], 0, 0, 0);
  }

#pragma unroll
  for (int j = 0; j < 4; ++j) {
    const int n = n0 + nh + j * 16 + fr;
    const float bv = bias ? bias[n] : 0.0f;
#pragma unroll
    for (int i = 0; i < 4; ++i) {
      const int mb = m0 + mh + i * 16 + (l >> 4) * 4;
#pragma unroll
      for (int r = 0; r < 4; ++r) {
        const float v = acc[i][j][r] + bv;
        const size_t ci = (size_t)(mb + r) * ldc + n;
        if constexpr (OUT_F16) ((half_t*)Cp)[ci] = (half_t)v;
        else                   ((float*)Cp)[ci] = v;
      }
    }
  }
}

// generic wrapper: grid.x = n-tiles (fast), grid.y = m-tiles
template <bool OUT_F16>
__global__ __launch_bounds__(256) void k_gemm_lds(const half_t* __restrict__ Ap,
                                                  const half_t* __restrict__ Bp,
                                                  const float* __restrict__ bias,
                                                  void* __restrict__ Cp,
                                                  int Kd, int ldc) {
  gemm128_body<OUT_F16>(Ap, Bp, bias, Cp, Kd, ldc,
                        blockIdx.y * 128, blockIdx.x * 128);
}

// kpfp GEMM: 1568 blocks, XCD-chunked (1568%8==0), works n-fast (8 n-tiles share A panel)
__global__ __launch_bounds__(256) void k_kpfp(const half_t* __restrict__ featf,
                                              const half_t* __restrict__ wkfc0,
                                              const float* __restrict__ biasc,
                                              half_t* __restrict__ kpfp) {
  const int w = (blockIdx.x & 7) * 196 + (blockIdx.x >> 3);
  const int n0 = (w & 7) * 128;
  const int m0 = (w >> 3) * 128;
  gemm128_body<true>(featf, wkfc0, biasc, kpfp, 512, 1024, m0, n0);
}

// final fc2 GEMM over all timesteps: C[1920][32000] = hall @ fc2w^T + fc2_b
// 3750 blocks, bijective XCD swizzle, works m-fast (15 m-tiles share each B panel)
__global__ __launch_bounds__(256) void k_fc2_final(const half_t* __restrict__ hall,
                                                   const half_t* __restrict__ fc2w,
                                                   const float* __restrict__ fc2b,
                                                   float* __restrict__ outp) {
  const int w = xcd_swz(blockIdx.x, 3750);
  const int m0 = (w % 15) * 128;
  const int n0 = (w / 15) * 128;
  gemm128_body<false>(hall, fc2w, fc2b, outp, 512, 32000, m0, n0);
}

// ---------------- scores: one wave per (b,s): tanh(q_b + kp_bs) . attv ----------------
__global__ __launch_bounds__(256) void k_scores(const half_t* __restrict__ kpfp,
                                                const float* __restrict__ ghq,
                                                const float* __restrict__ attv,
                                                float* __restrict__ scores) {
  int w = blockIdx.x * 4 + (threadIdx.x >> 6);   // 0..25087 == b*196+s
  int l = threadIdx.x & 63;
  int b = w / 196;
  halfx8 kv = *(const halfx8*)(kpfp + (size_t)w * 1024 + l * 8);
  const float* qr = ghq + (size_t)b * 2048 + 1536 + l * 8;
  float4 q0 = *(const float4*)qr;
  float4 q1 = *(const float4*)(qr + 4);
  float4 a0 = *(const float4*)(attv + l * 8);
  float4 a1 = *(const float4*)(attv + l * 8 + 4);
  float acc = a0.x * tanh_f(q0.x + (float)kv[0]);
  acc += a0.y * tanh_f(q0.y + (float)kv[1]);
  acc += a0.z * tanh_f(q0.z + (float)kv[2]);
  acc += a0.w * tanh_f(q0.w + (float)kv[3]);
  acc += a1.x * tanh_f(q1.x + (float)kv[4]);
  acc += a1.y * tanh_f(q1.y + (float)kv[5]);
  acc += a1.z * tanh_f(q1.z + (float)kv[6]);
  acc += a1.w * tanh_f(q1.w + (float)kv[7]);
#pragma unroll
  for (int off = 32; off > 0; off >>= 1) acc += __shfl_xor(acc, off, 64);
  if (l == 0) scores[w] = acc;
}

// ---------------- softmax + ctx = w @ featp (f16 out) ----------------
__global__ __launch_bounds__(256) void k_ctx(const float* __restrict__ scores,
                                             const half_t* __restrict__ kpfp,
                                             half_t* __restrict__ ctxo) {
  const int b = blockIdx.x, kt = blockIdx.y * 128, t = threadIdx.x;
  __shared__ float sw[196], red[256];
  float sc = (t < 196) ? scores[b * 196 + t] : -1e30f;
  red[t] = sc; __syncthreads();
  for (int o = 128; o > 0; o >>= 1) { if (t < o) red[t] = fmaxf(red[t], red[t + o]); __syncthreads(); }
  float mx = red[0]; __syncthreads();
  float e = (t < 196) ? __expf(sc - mx) : 0.f;
  red[t] = e; __syncthreads();
  for (int o = 128; o > 0; o >>= 1) { if (t < o) red[t] += red[t + o]; __syncthreads(); }
  float inv = 1.0f / red[0];
  if (t < 196) sw[t] = e * inv;
  __syncthreads();
  const int kk = t & 127, half = t >> 7, s0 = half * 98;
  const half_t* fp = kpfp + (size_t)(b * 196 + s0) * 1024 + 512 + kt + kk;
  float acc = 0.f;
#pragma unroll 7
  for (int i = 0; i < 98; ++i) acc += sw[s0 + i] * (float)fp[(size_t)i * 1024];
  red[t] = acc; __syncthreads();
  if (t < 128) ctxo[(size_t)b * 512 + kt + t] = (half_t)(red[t] + red[t + 128]);
}

// ---------------- GRU gates, elementwise; writes h_h (contiguous) and hall (b*15+t) ----
__global__ __launch_bounds__(256) void k_gates(const float* __restrict__ gix,
                                               const float* __restrict__ gic,
                                               const float* __restrict__ ghq,
                                               const float* __restrict__ bih,
                                               const float* __restrict__ bhh,
                                               float* __restrict__ hbuf,
                                               half_t* __restrict__ hh,
                                               half_t* __restrict__ hall, int step) {
  int idx = blockIdx.x * 256 + threadIdx.x;  // 0..65535
  int b = idx >> 9, n = idx & 511;
  const float* gx = gix + (size_t)(b * 15 + step) * 1536;
  const float* gc = gic + (size_t)b * 1536;
  const float* gh = ghq + (size_t)b * 2048;
  float ir  = gx[n]        + gc[n]        + bih[n];
  float iz  = gx[n + 512]  + gc[n + 512]  + bih[n + 512];
  float in_ = gx[n + 1024] + gc[n + 1024] + bih[n + 1024];
  float hr  = gh[n]        + bhh[n];
  float hz  = gh[n + 512]  + bhh[n + 512];
  float hn  = gh[n + 1024] + bhh[n + 1024];
  float r = sigmoid_f(ir + hr);
  float z = sigmoid_f(iz + hz);
  float nn = tanh_f(in_ + r * hn);
  float hv = (1.0f - z) * nn + z * hbuf[idx];
  hbuf[idx] = hv;
  half_t h16 = (half_t)hv;
  hh[idx] = h16;
  hall[(size_t)(b * 15 + step) * 512 + n] = h16;
}

extern "C" void kernel_launch(void* const* d_in, const int* in_sizes, int n_in,
                              void* d_out, int out_size, void* d_ws, size_t ws_size,
                              hipStream_t stream) {
  (void)in_sizes; (void)n_in; (void)out_size; (void)ws_size;
  const float* features = (const float*)d_in[0];
  const int*   captions = (const int*)d_in[1];
  const float* emb      = (const float*)d_in[2];
  const float* fc1_w    = (const float*)d_in[3];
  const float* fc1_b    = (const float*)d_in[4];
  const float* att_wq   = (const float*)d_in[5];
  const float* att_wk   = (const float*)d_in[6];
  const float* att_v    = (const float*)d_in[7];
  const float* fc0_w    = (const float*)d_in[8];
  const float* fc0_b    = (const float*)d_in[9];
  const float* gru_wih  = (const float*)d_in[10];
  const float* gru_whh  = (const float*)d_in[11];
  const float* gru_bih  = (const float*)d_in[12];
  const float* gru_bhh  = (const float*)d_in[13];
  const float* fc2_w    = (const float*)d_in[14];
  const float* fc2_b    = (const float*)d_in[15];
  float* out = (float*)d_out;

  // workspace layout (~137 MB)
  char* p = (char*)d_ws;
  half_t* kpfp   = (half_t*)p; p += (size_t)25088 * 1024 * 2; // [:,0:512]=kp, [:,512:1024]=featp+fc0_b
  half_t* fc2w_h = (half_t*)p; p += (size_t)32000 * 512 * 2;
  float*  gix    = (float*)p;  p += (size_t)1920 * 1536 * 4;  // x-path GRU gates, all t
  half_t* wihx_h = (half_t*)p; p += (size_t)1536 * 512 * 2;
  half_t* wihc_h = (half_t*)p; p += (size_t)1536 * 512 * 2;
  half_t* bcat2  = (half_t*)p; p += (size_t)2048 * 512 * 2;   // rows 0:1536=whh, 1536:2048=wq
  half_t* wkfc0  = (half_t*)p; p += (size_t)1024 * 512 * 2;   // rows 0:512=att_wk, 512:1024=fc0_w
  half_t* fc1w_h = (half_t*)p; p += (size_t)512 * 512 * 2;
  half_t* embg_h = (half_t*)p; p += (size_t)1920 * 512 * 2;
  half_t* xproj_h= (half_t*)p; p += (size_t)1920 * 512 * 2;
  float*  biasc  = (float*)p;  p += (size_t)1024 * 4;
  float*  ghq    = (float*)p;  p += (size_t)128 * 2048 * 4;   // cols 0:1536=gh, 1536:2048=q
  float*  hbuf   = (float*)p;  p += (size_t)128 * 512 * 4;    // contiguous after ghq (zeroed together)
  float*  scores = (float*)p;  p += (size_t)128 * 196 * 4;
  float*  gic    = (float*)p;  p += (size_t)128 * 1536 * 4;
  half_t* ctxo   = (half_t*)p; p += (size_t)128 * 512 * 2;
  half_t* h_h    = (half_t*)p; p += (size_t)128 * 512 * 2;
  half_t* featf  = (half_t*)p; p += (size_t)25088 * 512 * 2;  // features, f16
  half_t* hall   = (half_t*)p; p += (size_t)1920 * 512 * 2;   // all h_t, rows b*15+t

  // ---- precompute ----
  k_cvt_f16<<<dim3(16000), 256, 0, stream>>>(fc2_w, fc2w_h, 32000 * 512);
  k_cvt_f16<<<dim3(12544), 256, 0, stream>>>(features, featf, 25088 * 512);
  k_cvt_f16<<<dim3(256),   256, 0, stream>>>(fc1_w, fc1w_h, 512 * 512);
  k_cvt_f16<<<dim3(256),   256, 0, stream>>>(att_wk, wkfc0, 512 * 512);
  k_cvt_f16<<<dim3(256),   256, 0, stream>>>(fc0_w, wkfc0 + (size_t)512 * 512, 512 * 512);
  k_cvt_f16<<<dim3(768),   256, 0, stream>>>(gru_whh, bcat2, 1536 * 512);
  k_cvt_f16<<<dim3(256),   256, 0, stream>>>(att_wq, bcat2 + (size_t)1536 * 512, 512 * 512);
  k_wihsplit<<<dim3(1536), 256, 0, stream>>>(gru_wih, wihx_h, wihc_h);
  k_gather<<<dim3(1920), 256, 0, stream>>>(emb, captions, embg_h);
  k_biasc<<<dim3(4), 256, 0, stream>>>(fc0_b, biasc);
  // zero ghq (1 MB) + hbuf (256 KB): 81920 float4
  k_zero<<<dim3(320), 256, 0, stream>>>((float4*)ghq);
  // xproj = embg @ fc1_w^T + fc1_b  (1920 x 512, f16 out)
  k_gemm_lds<true><<<dim3(4, 15), 256, 0, stream>>>(embg_h, fc1w_h, fc1_b, xproj_h, 512, 512);
  // kpfp = featf @ [wk|fc0]^T + [0|fc0_b]  (25088 x 1024, f16 out), XCD-chunked
  k_kpfp<<<dim3(1568), 256, 0, stream>>>(featf, wkfc0, biasc, kpfp);
  // gix = xproj @ wihx^T  (1920 x 1536, f32 out)
  k_gemm_lds<false><<<dim3(12, 15), 256, 0, stream>>>(xproj_h, wihx_h, nullptr, gix, 512, 1536);

  // ---- decode loop ----
  for (int t = 0; t < 15; ++t) {
    k_scores<<<dim3(6272), 256, 0, stream>>>(kpfp, ghq, att_v, scores);
    k_ctx<<<dim3(128, 4), 256, 0, stream>>>(scores, kpfp, ctxo);
    // gic = ctxo @ wihc^T  (128 x 1536)
    k_gemm_lds<false><<<dim3(12, 1), 256, 0, stream>>>(ctxo, wihc_h, nullptr, gic, 512, 1536);
    k_gates<<<dim3(256), 256, 0, stream>>>(gix, gic, ghq, gru_bih, gru_bhh, hbuf, h_h, hall, t);
    // ghq = h @ [whh|wq]^T (for step t+1)  (128 x 2048)
    k_gemm_lds<false><<<dim3(16, 1), 256, 0, stream>>>(h_h, bcat2, nullptr, ghq, 512, 2048);
  }
  // out[b,t,:] = hall[b*15+t] @ fc2^T + fc2_b  (1920 x 32000), one big GEMM
  k_fc2_final<<<dim3(3750), 256, 0, stream>>>(hall, fc2w_h, fc2_b, out);
}